// Round 3
// baseline (185.464 us; speedup 1.0000x reference)
//
#include <hip/hip_runtime.h>

#define C 2
#define H 200
#define W 200
#define NN 200
#define N4 50                  // float4 groups along n
#define PLANE (H * W * NN)     // elements per data plane
#define PPT 8                  // pixels per thread
#define PIXPB 40               // pixels per block (5 groups * 8)

__global__ __launch_bounds__(256) void crop_split_kernel(
    const float* __restrict__ data,
    const float4* __restrict__ rois4,   // 200 x {x1,y1,x2,y2}
    float4* __restrict__ out)
{
    const int t = threadIdx.x;
    if (t >= 250) return;               // 250 active lanes (50 n-groups x 5 pixel-groups)
    const int n4   = t % 50;            // fixed n-group for this thread
    const int pcol = t / 50;            // which 8-pixel group within the block
    const int pixBase = blockIdx.x * PIXPB + pcol * PPT;   // block never crosses a row
    const int y  = pixBase / W;
    const int x0 = pixBase % W;
    const float fy = (float)y;

    // Load the 4 rois for n = 4*n4 .. 4*n4+3 ONCE (amortized over 8 pixels).
    float4 r[4];
#pragma unroll
    for (int k = 0; k < 4; ++k) r[k] = rois4[4 * n4 + k];

    // Hoist all y-dependent terms out of the pixel loop.
    // Bit-exact vs numpy float32: exact pow2 scale, one IEEE div, floorf, clamp.
    float cw[4];
    int   cyrow[4];
    bool  yin[4];
#pragma unroll
    for (int k = 0; k < 4; ++k) {
        cw[k] = fmaxf(r[k].z - r[k].x, 1.0f);
        const float ch = fmaxf(r[k].w - r[k].y, 1.0f);
        const float ty = (2.0f * (fy - r[k].y)) / ch;
        const int  cy  = (int)fminf(fmaxf(floorf(ty), 0.0f), (float)(C - 1));
        cyrow[k] = cy * C;
        yin[k]   = (fy >= r[k].y) & (fy <= r[k].w);
    }

    const int nbase = 4 * n4;           // scalar n offset within a pixel's 200-run

#pragma unroll
    for (int p = 0; p < PPT; ++p) {
        const int pix = pixBase + p;
        const float fx = (float)(x0 + p);
        const int pbase = pix * NN + nbase;

        float v[4];
#pragma unroll
        for (int k = 0; k < 4; ++k) {
            const bool inside = yin[k] & (fx >= r[k].x) & (fx <= r[k].z);
            float val = 0.0f;
            if (inside) {
                const float tx = (2.0f * (fx - r[k].x)) / cw[k];
                const int  cx  = (int)fminf(fmaxf(floorf(tx), 0.0f), (float)(C - 1));
                const int cell = cyrow[k] + cx;
                val = data[cell * PLANE + pbase + k];
            }
            v[k] = val;
        }
        out[pix * N4 + n4] = make_float4(v[0], v[1], v[2], v[3]);
    }
}

extern "C" void kernel_launch(void* const* d_in, const int* in_sizes, int n_in,
                              void* d_out, int out_size, void* d_ws, size_t ws_size,
                              hipStream_t stream) {
    const float* data  = (const float*)d_in[0];   // (4,200,200,200) f32
    const float4* rois = (const float4*)d_in[1];  // (200,4) f32
    float4* out = (float4*)d_out;                 // (200,200,200) f32 as float4

    const int blocks = (H * W) / PIXPB;           // 1000
    crop_split_kernel<<<blocks, 256, 0, stream>>>(data, rois, out);
}

// Round 4
// 181.142 us; speedup vs baseline: 1.0239x; 1.0239x over previous
//
#include <hip/hip_runtime.h>

#define C 2
#define H 200
#define W 200
#define NN 200
#define N4 50                   // float4 groups along n
#define TOTAL4 (H * W * N4)     // 2,000,000 float4 outputs
#define PLANE (H * W * NN)      // elements per data plane

typedef unsigned char uchar;
typedef unsigned int uint;

// Pre-kernel: per-(coord, n) byte tables.
//   cxb[x*NN + n] : bit0 = cx (0/1), bit1 = (x1 <= x <= x2)
//   cyb[y*NN + n] : bit0 = cy (0/1), bit1 = (y1 <= y <= y2)
// Same float32 expression as the reference (exact pow2 scale, one IEEE div,
// floorf, clamp) -> bit-exact cell indices.
__global__ __launch_bounds__(256) void prep_kernel(
    const float4* __restrict__ rois4, uchar* __restrict__ cxb, uchar* __restrict__ cyb)
{
    const int i = blockIdx.x * 256 + threadIdx.x;
    if (i >= 2 * W * NN) return;
    const bool isY = (i >= W * NN);
    const int j = isY ? i - W * NN : i;
    const int coord = j / NN;
    const int n = j % NN;
    const float4 r = rois4[n];
    const float lo = isY ? r.y : r.x;
    const float hi = isY ? r.w : r.z;
    const float f = (float)coord;
    const bool in = (f >= lo) & (f <= hi);
    const float cw = fmaxf(hi - lo, 1.0f);
    const float t = (2.0f * (f - lo)) / cw;
    const int c = (int)fminf(fmaxf(floorf(t), 0.0f), (float)(C - 1));
    const uchar b = (uchar)((in ? 2 : 0) | c);
    (isY ? cyb : cxb)[j] = b;
}

__global__ __launch_bounds__(256) void crop_split_kernel(
    const float* __restrict__ data,
    const uchar* __restrict__ cxb,
    const uchar* __restrict__ cyb,
    float4* __restrict__ out)
{
    const int j = blockIdx.x * 256 + threadIdx.x;
    if (j >= TOTAL4) return;

    const int n4  = j % N4;        // float4 group along n (consecutive across lanes)
    const int pix = j / N4;        // y*W + x
    const int x   = pix % W;
    const int y   = pix / W;
    const int nb  = n4 * 4;

    // 4 n's worth of table bytes in one aligned u32 load each (coalesced).
    const uint cxw = *(const uint*)(cxb + x * NN + nb);
    const uint cyw = *(const uint*)(cyb + y * NN + nb);

    const int pbase = pix * NN + nb;

    float v[4];
#pragma unroll
    for (int k = 0; k < 4; ++k) {
        const uint bx = (cxw >> (8 * k)) & 0xffu;
        const uint by = (cyw >> (8 * k)) & 0xffu;
        float val = 0.0f;
        if ((bx & by & 2u) != 0u) {
            const int cell = (int)(((by & 1u) << 1) | (bx & 1u));
            val = data[cell * PLANE + pbase + k];
        }
        v[k] = val;
    }
    out[j] = make_float4(v[0], v[1], v[2], v[3]);
}

extern "C" void kernel_launch(void* const* d_in, const int* in_sizes, int n_in,
                              void* d_out, int out_size, void* d_ws, size_t ws_size,
                              hipStream_t stream) {
    const float* data  = (const float*)d_in[0];   // (4,200,200,200) f32
    const float4* rois = (const float4*)d_in[1];  // (200,4) f32
    float4* out = (float4*)d_out;                 // (200,200,200) f32 as float4

    uchar* cxb = (uchar*)d_ws;                    // 40 kB
    uchar* cyb = cxb + (size_t)W * NN;            // 40 kB

    prep_kernel<<<(2 * W * NN + 255) / 256, 256, 0, stream>>>(rois, cxb, cyb);
    crop_split_kernel<<<(TOTAL4 + 255) / 256, 256, 0, stream>>>(data, cxb, cyb, out);
}